// Round 11
// baseline (102.436 us; speedup 1.0000x reference)
//
#include <hip/hip_runtime.h>

#define NN 8192
#define EE 256
#define KNH 32
#define NKEEP 4096
#define NCX 64
#define NCELL 4096
#define CNT_MIN 48
#define CACHE_CAP 512

typedef unsigned long long u64;
typedef unsigned int u32;

// ws layout:
// part  @ 0      [2][32][256] f32   (65536)
// gm    @ 65536  [2][256] f32       ( 2048)
// start @ 67584  [2][4097] int      (32800 alloc)
// sc    @ 100384 [2][8192] float2   (131072)
// sj    @ 231456 [2][8192] int      (65536)   -> 296992 total

__device__ __forceinline__ int cellof(float v) {
    const int q = (int)floorf((v + 4.6f) * (64.0f / 9.2f));
    return min(max(q, 0), NCX - 1);
}

__global__ void k_gm_partial(const float* __restrict__ x, float* __restrict__ part) {
    const int b = blockIdx.y, chunk = blockIdx.x, t = threadIdx.x;
    const float* xp = x + ((size_t)b * NN + (size_t)chunk * 256) * EE + t;
    float s = 0.0f;
    for (int i = 0; i < 256; ++i) s += xp[(size_t)i * EE];
    part[((size_t)b * 32 + chunk) * EE + t] = s;
}

__global__ void k_gm_final(const float* __restrict__ part, float* __restrict__ gm) {
    const int b = blockIdx.y, t = threadIdx.x;
    float s = 0.0f;
    for (int c = 0; c < 32; ++c) s += part[((size_t)b * 32 + c) * EE + t];
    gm[b * EE + t] = fabsf(s / (float)NN);
}

// fused per-batch binning: count (LDS atomics) -> wave-scan -> scatter.
__global__ void __launch_bounds__(1024) k_binning(const float* __restrict__ coords,
                                                  int* __restrict__ start,
                                                  float2* __restrict__ sc,
                                                  int* __restrict__ sj) {
    __shared__ int cnt[NCELL];
    __shared__ int wsum[16];
    const int b = blockIdx.x, t = threadIdx.x;
    const int lane = t & 63, wv = t >> 6;
#pragma unroll
    for (int k = 0; k < 4; ++k) cnt[k * 1024 + t] = 0;
    __syncthreads();
#pragma unroll
    for (int k = 0; k < 8; ++k) {
        const int i = k * 1024 + t;
        const float xv = coords[(size_t)b * 2 * NN + i];
        const float yv = coords[(size_t)b * 2 * NN + NN + i];
        atomicAdd(&cnt[cellof(xv) * NCX + cellof(yv)], 1);
    }
    __syncthreads();
    const int v0 = cnt[t * 4 + 0], v1 = cnt[t * 4 + 1];
    const int v2 = cnt[t * 4 + 2], v3 = cnt[t * 4 + 3];
    const int s = v0 + v1 + v2 + v3;
    int inc = s;
#pragma unroll
    for (int d = 1; d < 64; d <<= 1) {
        const int u = __shfl_up(inc, d);
        inc += (lane >= d) ? u : 0;
    }
    if (lane == 63) wsum[wv] = inc;
    __syncthreads();
    int wpre = 0;
#pragma unroll
    for (int w = 0; w < 16; ++w) wpre += (w < wv) ? wsum[w] : 0;
    int run = wpre + inc - s;
    start[b * (NCELL + 1) + t * 4 + 0] = run; cnt[t * 4 + 0] = run; run += v0;
    start[b * (NCELL + 1) + t * 4 + 1] = run; cnt[t * 4 + 1] = run; run += v1;
    start[b * (NCELL + 1) + t * 4 + 2] = run; cnt[t * 4 + 2] = run; run += v2;
    start[b * (NCELL + 1) + t * 4 + 3] = run; cnt[t * 4 + 3] = run; run += v3;
    if (t == 0) start[b * (NCELL + 1) + NCELL] = NN;
    __syncthreads();
#pragma unroll
    for (int k = 0; k < 8; ++k) {
        const int i = k * 1024 + t;
        const float xv = coords[(size_t)b * 2 * NN + i];
        const float yv = coords[(size_t)b * 2 * NN + NN + i];
        const int p = atomicAdd(&cnt[cellof(xv) * NCX + cellof(yv)], 1);
        sc[(size_t)b * NN + p] = make_float2(xv, yv);
        sj[(size_t)b * NN + p] = i;
    }
}

__device__ __forceinline__ u64 shfl_xor_u64(u64 v, int m) {
    const u32 hi = (u32)__shfl_xor((int)(u32)(v >> 32), m);
    const u32 lo = (u32)__shfl_xor((int)(u32)v, m);
    return ((u64)hi << 32) | lo;
}

__device__ __forceinline__ u64 wave_min_u64(u64 h) {
#pragma unroll
    for (int s = 1; s < 64; s <<= 1) {
        const u64 o = shfl_xor_u64(h, s);
        h = (o < h) ? o : h;
    }
    return h;
}

// One wave per scatter-order point. Adaptive square (>=CNT_MIN cands),
// pass 1: flattened stream, per-lane min, (d,j) cached in LDS.
// T = 32nd smallest lane-min via ballot binary search (valid upper bound).
// Pass 2: survivors (d<=T) from LDS cache (or global re-walk if the sqrt(T)
// box escapes the pass-1 box / cache overflow) -> ballot-compact to comp.
// Selection: exact top-32 SET by (d_bits, j) via ballot binary searches
// (d32 + index-cut among ties) -- no sort; set semantics match top_k since
// mean/std are permutation-invariant. Certificates -> exact argmin fallback.
__global__ void __launch_bounds__(256) k_knn_dist(
        const float* __restrict__ x,
        const float* __restrict__ gm, const float2* __restrict__ sc,
        const int* __restrict__ sj, const int* __restrict__ start,
        float* __restrict__ ld_out) {
    __shared__ u64 cache[4][CACHE_CAP];
    __shared__ u64 comp[4][64];
    const int wg   = blockIdx.x;
    const int swz  = (wg & 7) * 512 + (wg >> 3);   // XCD-chunked, bijective
    const int b    = swz >> 11;
    const int pb   = swz & 2047;
    const int wid  = threadIdx.x >> 6;
    const int lane = threadIdx.x & 63;
    const int p    = pb * 4 + wid;

    const float2* scb = sc + (size_t)b * NN;
    const int*    sjb = sj + (size_t)b * NN;
    const int*    stb = start + b * (NCELL + 1);
    const float2 cp = scb[p];
    const int    i  = sjb[p];
    const float ci0 = cp.x, ci1 = cp.y;
    const int qx = cellof(ci0), qy = cellof(ci1);

    // ---- adaptive square: double r until count >= CNT_MIN ----
    int r = 1, xl1, xh1, yl1, yh1, nsl;
    int myc0 = 0, mylen = 0;
    for (;;) {
        xl1 = max(qx - r, 0);
        xh1 = min(qx + r, NCX - 1);
        yl1 = max(qy - r, 0);
        yh1 = min(qy + r, NCX - 1);
        nsl = xh1 - xl1 + 1;
        int c0 = 0, c1 = 0;
        if (lane < nsl) {
            c0 = stb[(xl1 + lane) * NCX + yl1];
            c1 = stb[(xl1 + lane) * NCX + yh1 + 1];
        }
        myc0 = c0; mylen = c1 - c0;
        int tot = mylen;
#pragma unroll
        for (int s = 1; s < 64; s <<= 1) tot += __shfl_xor(tot, s);
        if (tot >= CNT_MIN || r >= NCX) break;
        r <<= 1;
    }
    int incl = mylen;
#pragma unroll
    for (int d = 1; d < 64; d <<= 1) {
        const int v = __shfl_up(incl, d);
        incl += (lane >= d) ? v : 0;
    }
    int excl = incl - mylen;
    const int L1 = __shfl(incl, 63);

    // ---- pass 1: per-lane min over flattened stream; cache (d,j) in LDS ----
    float dmin = 1e30f;
    for (int g = 0; g < L1; g += 64) {
        const int gp = g + lane;
        int lo = 0, hi = nsl - 1;
#pragma unroll
        for (int st = 0; st < 6; ++st) {
            const int mid = (lo + hi + 1) >> 1;
            const int v = __shfl(excl, mid);
            const bool go = (v <= gp);
            lo = go ? mid : lo;
            hi = go ? hi : mid - 1;
        }
        const int cnd = __shfl(myc0, lo) + gp - __shfl(excl, lo);
        const int cc  = min(max(cnd, 0), NN - 1);
        const float2 pt = scb[cc];
        const int    jj = sjb[cc];
        const float dx = ci0 - pt.x, dy = ci1 - pt.y;
        const float d  = fmaf(dx, dx, dy * dy);
        if (gp < L1) {
            dmin = fminf(dmin, d);
            if (gp < CACHE_CAP) cache[wid][gp] = ((u64)__float_as_uint(d) << 32) | (u32)jj;
        }
    }

    // ---- T = 32nd smallest of the 64 lane minima (ballot binary search) ----
    const u32 kmin = __float_as_uint(dmin);
    u32 blo = 0, bhi = 0xFFFFFFFFu;
    for (int it = 0; it < 32; ++it) {
        const u32 mid = blo + ((bhi - blo) >> 1);
        const int c = __popcll(__ballot(kmin <= mid));
        if (c >= KNH) bhi = mid; else blo = mid + 1;
    }
    const u32 T = bhi;

    // ---- pass-2 box from sqrt(T) ----
    const float srad = sqrtf(__uint_as_float(T)) * 1.0002f + 1e-5f;
    const int xl2 = cellof(ci0 - srad), xh2 = cellof(ci0 + srad);
    const int yl2 = cellof(ci1 - srad), yh2 = cellof(ci1 + srad);
    const bool cached = (L1 <= CACHE_CAP) && (xl2 >= xl1) && (xh2 <= xh1) &&
                        (yl2 >= yl1) && (yh2 <= yh1);

    const u64 lmask = (1ull << lane) - 1;
    int base = 0;
    if (cached) {
        for (int g = 0; g < L1; g += 64) {
            const int gp = g + lane;
            u64 e = ~0ull;
            if (gp < L1) e = cache[wid][gp];
            const bool keep = (gp < L1) && ((u32)(e >> 32) <= T);
            const u64 m = __ballot(keep);
            const int pos = base + __popcll(m & lmask);
            base += __popcll(m);
            if (keep && pos < 64) comp[wid][pos] = e;
        }
    } else {
        const int nsl2 = xh2 - xl2 + 1;
        int c0 = 0, c1 = 0;
        if (lane < nsl2) {
            c0 = stb[(xl2 + lane) * NCX + yl2];
            c1 = stb[(xl2 + lane) * NCX + yh2 + 1];
        }
        const int myc2 = c0;
        const int len2 = c1 - c0;
        int incl2 = len2;
#pragma unroll
        for (int d = 1; d < 64; d <<= 1) {
            const int v = __shfl_up(incl2, d);
            incl2 += (lane >= d) ? v : 0;
        }
        const int excl2 = incl2 - len2;
        const int L2 = __shfl(incl2, 63);
        for (int g = 0; g < L2; g += 64) {
            const int gp = g + lane;
            int lo = 0, hi = nsl2 - 1;
#pragma unroll
            for (int st = 0; st < 6; ++st) {
                const int mid = (lo + hi + 1) >> 1;
                const int v = __shfl(excl2, mid);
                const bool go = (v <= gp);
                lo = go ? mid : lo;
                hi = go ? hi : mid - 1;
            }
            const int cnd = __shfl(myc2, lo) + gp - __shfl(excl2, lo);
            const int cc  = min(max(cnd, 0), NN - 1);
            const float2 pt = scb[cc];
            const int    jj = sjb[cc];
            const float dx = ci0 - pt.x, dy = ci1 - pt.y;
            const u32 db = __float_as_uint(fmaf(dx, dx, dy * dy));
            const bool keep = (gp < L2) && (db <= T);
            const u64 m = __ballot(keep);
            const int pos = base + __popcll(m & lmask);
            base += __popcll(m);
            if (keep && pos < 64) comp[wid][pos] = ((u64)db << 32) | (u32)jj;
        }
    }
    const bool ovf = (base > 64) || (base < KNH);

    // ---- exact top-32 SET by (d_bits, j): ballot searches, no sort ----
    u64 key = ~0ull;
    if (lane < base && lane < 64) key = comp[wid][lane];
    const u32 dbl = (u32)(key >> 32);
    const u32 jl  = (u32)key;
    const bool act = (lane < base) && (lane < 64);

    u32 slo = 0, shi = 0xFFFFFFFFu;
    for (int it = 0; it < 32; ++it) {
        const u32 mid = slo + ((shi - slo) >> 1);
        const int c = __popcll(__ballot(act && dbl <= mid));
        if (c >= KNH) shi = mid; else slo = mid + 1;
    }
    const u32 d32b = shi;
    const int cnt_lt = __popcll(__ballot(act && dbl < d32b));
    const int need = KNH - cnt_lt;
    u32 jlo = 0, jhi = 0xFFFFFFFFu;
    for (int it = 0; it < 32; ++it) {
        const u32 mid = jlo + ((jhi - jlo) >> 1);
        const int c = __popcll(__ballot(act && (dbl == d32b) && (jl <= mid)));
        if (c >= need) jhi = mid; else jlo = mid + 1;
    }
    const u32 jcut = jhi;
    const bool sel = act && ((dbl < d32b) || ((dbl == d32b) && (jl <= jcut)));
    u64 selmask = __ballot(sel);
    int jsel = (int)jl;

    // ---- certificate fallback: exact 32-round argmin over box2 ----
    if (ovf) {
        const int nsl2 = xh2 - xl2 + 1;
        int c0 = 0, c1 = 0;
        if (lane < nsl2) {
            c0 = stb[(xl2 + lane) * NCX + yl2];
            c1 = stb[(xl2 + lane) * NCX + yh2 + 1];
        }
        const int myc2 = c0;
        const int len2 = c1 - c0;
        int incl2 = len2;
#pragma unroll
        for (int d = 1; d < 64; d <<= 1) {
            const int v = __shfl_up(incl2, d);
            incl2 += (lane >= d) ? v : 0;
        }
        const int excl2 = incl2 - len2;
        const int L2 = __shfl(incl2, 63);
        int jkeep = 0;
        u64 minkeep = 0;
        for (int k = 0; k < KNH; ++k) {
            u64 best = ~0ull;
            for (int g = 0; g < L2; g += 64) {
                const int gp = g + lane;
                int lo = 0, hi = nsl2 - 1;
#pragma unroll
                for (int st = 0; st < 6; ++st) {
                    const int mid = (lo + hi + 1) >> 1;
                    const int v = __shfl(excl2, mid);
                    const bool go = (v <= gp);
                    lo = go ? mid : lo;
                    hi = go ? hi : mid - 1;
                }
                const int cnd = __shfl(myc2, lo) + gp - __shfl(excl2, lo);
                const int cc  = min(max(cnd, 0), NN - 1);
                const float2 pt = scb[cc];
                const int    jj = sjb[cc];
                const float dx = ci0 - pt.x, dy = ci1 - pt.y;
                const float d  = fmaf(dx, dx, dy * dy);
                const u64 kk = ((u64)__float_as_uint(d) << 32) | (u32)jj;
                if (gp < L2 && kk >= minkeep && kk < best) best = kk;
            }
            const u64 h = wave_min_u64(best);
            if (lane == k) jkeep = (int)(u32)h;
            minkeep = h + 1;
        }
        jsel = jkeep;
        selmask = 0xFFFFFFFFull;   // lanes 0..31 hold the selection
    }

    // ---- gather 32 rows via ffs+readlane (scalar pipe), f32 sum/sumsq ----
    float s1[4] = {0.f, 0.f, 0.f, 0.f};
    float s2[4] = {0.f, 0.f, 0.f, 0.f};
    const float* xb = x + (size_t)b * NN * EE;
    u64 m = selmask;
#pragma unroll 8
    for (int k = 0; k < KNH; ++k) {
        const int l = __ffsll((unsigned long long)m) - 1;
        m &= m - 1;
        const int j = __builtin_amdgcn_readlane(jsel, l);
        const float4 v = *reinterpret_cast<const float4*>(xb + (size_t)j * EE + (lane << 2));
        s1[0] += v.x; s2[0] += v.x * v.x;
        s1[1] += v.y; s2[1] += v.y * v.y;
        s1[2] += v.z; s2[2] += v.z * v.z;
        s1[3] += v.w; s2[3] += v.w * v.w;
    }

    const float* gmb = gm + b * EE;
    float tt = 0.f;
#pragma unroll
    for (int q = 0; q < 4; ++q) {
        const float sum = s1[q];
        float ssd = s2[q] - sum * sum * (1.0f / 32.0f);
        ssd = ssd > 0.f ? ssd : 0.f;
        const float ls = sqrtf(ssd * (1.0f / 31.0f));
        tt += ls / gmb[(lane << 2) + q];
    }
#pragma unroll
    for (int s2r = 1; s2r < 64; s2r <<= 1) tt += __shfl_xor(tt, s2r);

    if (lane == 0) ld_out[(size_t)b * NN + i] = tt;
}

// one wave per point: exact rank (desc, index tie-break) + direct row gather
__global__ void k_rank_gather(const float* __restrict__ x, const float* __restrict__ coords,
                              const float* __restrict__ ld,
                              float* __restrict__ x_out, float* __restrict__ c_out) {
    const int b    = blockIdx.y;
    const int wid  = threadIdx.x >> 6;
    const int lane = threadIdx.x & 63;
    const int i    = blockIdx.x * 4 + wid;
    const float* lb = ld + (size_t)b * NN;
    const float di = lb[i];
    int cnt = 0;
    for (int t = 0; t < NN / 256; ++t) {
        const int j0 = t * 256 + (lane << 2);
        const float4 dv = *reinterpret_cast<const float4*>(lb + j0);
        cnt += (dv.x > di || (dv.x == di && (j0 + 0) < i)) ? 1 : 0;
        cnt += (dv.y > di || (dv.y == di && (j0 + 1) < i)) ? 1 : 0;
        cnt += (dv.z > di || (dv.z == di && (j0 + 2) < i)) ? 1 : 0;
        cnt += (dv.w > di || (dv.w == di && (j0 + 3) < i)) ? 1 : 0;
    }
#pragma unroll
    for (int s = 1; s < 64; s <<= 1) cnt += __shfl_xor(cnt, s);

    if (cnt < NKEEP) {
        const float4 v = *reinterpret_cast<const float4*>(x + ((size_t)b * NN + i) * EE + (lane << 2));
        *reinterpret_cast<float4*>(x_out + ((size_t)b * NKEEP + cnt) * EE + (lane << 2)) = v;
        if (lane < 2) {
            c_out[((size_t)b * 2 + lane) * NKEEP + cnt] = coords[((size_t)b * 2 + lane) * NN + i];
        }
    }
}

extern "C" void kernel_launch(void* const* d_in, const int* in_sizes, int n_in,
                              void* d_out, int out_size, void* d_ws, size_t ws_size,
                              hipStream_t stream) {
    const float* x      = (const float*)d_in[0];
    const float* coords = (const float*)d_in[1];

    float* out    = (float*)d_out;
    float* x_out  = out;                 // [2][4096][256]
    float* c_out  = out + 2097152;       // [2][2][4096][1]
    float* ld_out = out + 2113536;       // [2][8192]

    char*   ws    = (char*)d_ws;
    float*  part  = (float*)(ws);
    float*  gm    = (float*)(ws + 65536);
    int*    start = (int*)  (ws + 67584);
    float2* sc    = (float2*)(ws + 100384);
    int*    sj    = (int*)  (ws + 231456);

    k_binning    <<<2,             1024, 0, stream>>>(coords, start, sc, sj);
    k_gm_partial <<<dim3(32, 2),   256,  0, stream>>>(x, part);
    k_gm_final   <<<dim3(1, 2),    256,  0, stream>>>(part, gm);
    k_knn_dist   <<<4096,          256,  0, stream>>>(x, gm, sc, sj, start, ld_out);
    k_rank_gather<<<dim3(2048, 2), 256,  0, stream>>>(x, coords, ld_out, x_out, c_out);
}

// Round 12
// 86.254 us; speedup vs baseline: 1.1876x; 1.1876x over previous
//
#include <hip/hip_runtime.h>

#define NN 8192
#define EE 256
#define KNH 32
#define NKEEP 4096
#define NCX 64
#define NCELL 4096
#define CNT_MIN 48

typedef unsigned long long u64;
typedef unsigned int u32;

// ws layout:
// part  @ 0      [2][32][256] f32   (65536)
// gm    @ 65536  [2][256] f32       ( 2048)
// start @ 67584  [2][4097] int      (32800 alloc)
// sc    @ 100384 [2][8192] float2   (131072)
// sj    @ 231456 [2][8192] int      (65536)   -> 296992 total

__device__ __forceinline__ int cellof(float v) {
    const int q = (int)floorf((v + 4.6f) * (64.0f / 9.2f));
    return min(max(q, 0), NCX - 1);
}

// fused: blocks 0-1 = per-batch binning (count -> wave-scan -> scatter);
// blocks 2-17 = gm column-sum partials (4 units of 256 threads each).
__global__ void __launch_bounds__(1024) k_pre(const float* __restrict__ coords,
                                              const float* __restrict__ x,
                                              int* __restrict__ start,
                                              float2* __restrict__ sc,
                                              int* __restrict__ sj,
                                              float* __restrict__ part) {
    __shared__ int cnt[NCELL];
    __shared__ int wsum[16];
    const int blk = blockIdx.x;
    if (blk >= 2) {
        const int unit  = (blk - 2) * 4 + (threadIdx.x >> 8);
        const int b     = unit >> 5;
        const int chunk = unit & 31;
        const int t     = threadIdx.x & 255;
        const float* xp = x + ((size_t)b * NN + (size_t)chunk * 256) * EE + t;
        float s = 0.0f;
        for (int i = 0; i < 256; ++i) s += xp[(size_t)i * EE];
        part[((size_t)b * 32 + chunk) * EE + t] = s;
        return;
    }
    const int b = blk, t = threadIdx.x;
    const int lane = t & 63, wv = t >> 6;
#pragma unroll
    for (int k = 0; k < 4; ++k) cnt[k * 1024 + t] = 0;
    __syncthreads();
#pragma unroll
    for (int k = 0; k < 8; ++k) {
        const int i = k * 1024 + t;
        const float xv = coords[(size_t)b * 2 * NN + i];
        const float yv = coords[(size_t)b * 2 * NN + NN + i];
        atomicAdd(&cnt[cellof(xv) * NCX + cellof(yv)], 1);
    }
    __syncthreads();
    const int v0 = cnt[t * 4 + 0], v1 = cnt[t * 4 + 1];
    const int v2 = cnt[t * 4 + 2], v3 = cnt[t * 4 + 3];
    const int s = v0 + v1 + v2 + v3;
    int inc = s;
#pragma unroll
    for (int d = 1; d < 64; d <<= 1) {
        const int u = __shfl_up(inc, d);
        inc += (lane >= d) ? u : 0;
    }
    if (lane == 63) wsum[wv] = inc;
    __syncthreads();
    int wpre = 0;
#pragma unroll
    for (int w = 0; w < 16; ++w) wpre += (w < wv) ? wsum[w] : 0;
    int run = wpre + inc - s;
    start[b * (NCELL + 1) + t * 4 + 0] = run; cnt[t * 4 + 0] = run; run += v0;
    start[b * (NCELL + 1) + t * 4 + 1] = run; cnt[t * 4 + 1] = run; run += v1;
    start[b * (NCELL + 1) + t * 4 + 2] = run; cnt[t * 4 + 2] = run; run += v2;
    start[b * (NCELL + 1) + t * 4 + 3] = run; cnt[t * 4 + 3] = run; run += v3;
    if (t == 0) start[b * (NCELL + 1) + NCELL] = NN;
    __syncthreads();
#pragma unroll
    for (int k = 0; k < 8; ++k) {
        const int i = k * 1024 + t;
        const float xv = coords[(size_t)b * 2 * NN + i];
        const float yv = coords[(size_t)b * 2 * NN + NN + i];
        const int p = atomicAdd(&cnt[cellof(xv) * NCX + cellof(yv)], 1);
        sc[(size_t)b * NN + p] = make_float2(xv, yv);
        sj[(size_t)b * NN + p] = i;
    }
}

__global__ void k_gm_final(const float* __restrict__ part, float* __restrict__ gm) {
    const int b = blockIdx.y, t = threadIdx.x;
    float s = 0.0f;
    for (int c = 0; c < 32; ++c) s += part[((size_t)b * 32 + c) * EE + t];
    gm[b * EE + t] = fabsf(s / (float)NN);
}

__device__ __forceinline__ u64 shfl_xor_u64(u64 v, int m) {
    const u32 hi = (u32)__shfl_xor((int)(u32)(v >> 32), m);
    const u32 lo = (u32)__shfl_xor((int)(u32)v, m);
    return ((u64)hi << 32) | lo;
}

__device__ __forceinline__ u64 wave_min_u64(u64 h) {
#pragma unroll
    for (int s = 1; s < 64; s <<= 1) {
        const u64 o = shfl_xor_u64(h, s);
        h = (o < h) ? o : h;
    }
    return h;
}

// Round-10 version (measured 48.1 us): adaptive square, flattened stream,
// bitonic T, ballot-compact, u64 bitonic sort, certificates -> fallback.
__global__ void __launch_bounds__(256) k_knn_dist(
        const float* __restrict__ x,
        const float* __restrict__ gm, const float2* __restrict__ sc,
        const int* __restrict__ sj, const int* __restrict__ start,
        float* __restrict__ ld_out) {
    __shared__ u64 comp[4][64];
    const int wg   = blockIdx.x;
    const int swz  = (wg & 7) * 512 + (wg >> 3);   // XCD-chunked, bijective
    const int b    = swz >> 11;
    const int pb   = swz & 2047;
    const int wid  = threadIdx.x >> 6;
    const int lane = threadIdx.x & 63;
    const int p    = pb * 4 + wid;

    const float2* scb = sc + (size_t)b * NN;
    const int*    sjb = sj + (size_t)b * NN;
    const int*    stb = start + b * (NCELL + 1);
    const float2 cp = scb[p];
    const int    i  = sjb[p];
    const float ci0 = cp.x, ci1 = cp.y;
    const int qx = cellof(ci0), qy = cellof(ci1);

    // ---- adaptive square: double r until count >= CNT_MIN ----
    int r = 1, xl, yl, yh, nsl;
    int myc0 = 0, mylen = 0;
    for (;;) {
        xl = max(qx - r, 0);
        const int xh = min(qx + r, NCX - 1);
        yl = max(qy - r, 0);
        yh = min(qy + r, NCX - 1);
        nsl = xh - xl + 1;
        int c0 = 0, c1 = 0;
        if (lane < nsl) {
            c0 = stb[(xl + lane) * NCX + yl];
            c1 = stb[(xl + lane) * NCX + yh + 1];
        }
        myc0 = c0; mylen = c1 - c0;
        int tot = mylen;
#pragma unroll
        for (int s = 1; s < 64; s <<= 1) tot += __shfl_xor(tot, s);
        if (tot >= CNT_MIN || r >= NCX) break;
        r <<= 1;
    }
    int incl = mylen;
#pragma unroll
    for (int d = 1; d < 64; d <<= 1) {
        const int v = __shfl_up(incl, d);
        incl += (lane >= d) ? v : 0;
    }
    int excl = incl - mylen;
    const int L1 = __shfl(incl, 63);

    // ---- pass 1: per-lane min over flattened stream ----
    float dmin = 1e30f;
    for (int g = 0; g < L1; g += 64) {
        const int gp = g + lane;
        int lo = 0, hi = nsl - 1;
#pragma unroll
        for (int st = 0; st < 6; ++st) {
            const int mid = (lo + hi + 1) >> 1;
            const int v = __shfl(excl, mid);
            const bool go = (v <= gp);
            lo = go ? mid : lo;
            hi = go ? hi : mid - 1;
        }
        const int cnd = __shfl(myc0, lo) + gp - __shfl(excl, lo);
        const int cc  = min(max(cnd, 0), NN - 1);
        const float2 pt = scb[cc];
        const float dx = ci0 - pt.x, dy = ci1 - pt.y;
        const float d  = fmaf(dx, dx, dy * dy);
        if (gp < L1) dmin = fminf(dmin, d);
    }

    // ---- T = 32nd smallest of the 64 lane minima (u32 bitonic sort) ----
    u32 mk = __float_as_uint(dmin);
#pragma unroll
    for (int k = 2; k <= 64; k <<= 1) {
#pragma unroll
        for (int j = k >> 1; j > 0; j >>= 1) {
            const u32 o = (u32)__shfl_xor((int)mk, j);
            const bool keep_min = (((lane & j) == 0) == ((lane & k) == 0));
            const u32 mn = min(mk, o), mx = max(mk, o);
            mk = keep_min ? mn : mx;
        }
    }
    const u32 T = (u32)__shfl((int)mk, 31);

    // ---- pass 2: flatten the sqrt(T)-box, ballot-compact survivors ----
    const float srad = sqrtf(__uint_as_float(T)) * 1.0002f + 1e-5f;
    xl = cellof(ci0 - srad);
    const int xh2 = cellof(ci0 + srad);
    yl = cellof(ci1 - srad);
    yh = cellof(ci1 + srad);
    nsl = xh2 - xl + 1;
    {
        int c0 = 0, c1 = 0;
        if (lane < nsl) {
            c0 = stb[(xl + lane) * NCX + yl];
            c1 = stb[(xl + lane) * NCX + yh + 1];
        }
        myc0 = c0; mylen = c1 - c0;
    }
    incl = mylen;
#pragma unroll
    for (int d = 1; d < 64; d <<= 1) {
        const int v = __shfl_up(incl, d);
        incl += (lane >= d) ? v : 0;
    }
    excl = incl - mylen;
    const int L2 = __shfl(incl, 63);

    const u64 lmask = (1ull << lane) - 1;
    int base = 0;
    for (int g = 0; g < L2; g += 64) {
        const int gp = g + lane;
        int lo = 0, hi = nsl - 1;
#pragma unroll
        for (int st = 0; st < 6; ++st) {
            const int mid = (lo + hi + 1) >> 1;
            const int v = __shfl(excl, mid);
            const bool go = (v <= gp);
            lo = go ? mid : lo;
            hi = go ? hi : mid - 1;
        }
        const int cnd = __shfl(myc0, lo) + gp - __shfl(excl, lo);
        const int cc  = min(max(cnd, 0), NN - 1);
        const float2 pt = scb[cc];
        const int    jj = sjb[cc];
        const float dx = ci0 - pt.x, dy = ci1 - pt.y;
        const u32 db = __float_as_uint(fmaf(dx, dx, dy * dy));
        const bool keep = (gp < L2) && (db <= T);
        const u64 m = __ballot(keep);
        const int pos = base + __popcll(m & lmask);
        base += __popcll(m);
        if (keep && pos < 64) comp[wid][pos] = ((u64)db << 32) | (u32)jj;
    }
    const bool ovf = (base > 64) || (base < KNH);

    // ---- bitonic sort (ascending) of up to 64 survivor keys ----
    u64 key = (lane < base) ? comp[wid][lane] : ~0ull;
#pragma unroll
    for (int k = 2; k <= 64; k <<= 1) {
#pragma unroll
        for (int j = k >> 1; j > 0; j >>= 1) {
            const u64 other = shfl_xor_u64(key, j);
            const bool keep_min = (((lane & j) == 0) == ((lane & k) == 0));
            const bool lt = (key < other);
            const u64 mn = lt ? key : other;
            const u64 mx = lt ? other : key;
            key = keep_min ? mn : mx;
        }
    }
    int jkeep = (int)(u32)key;   // lane m (m<32) holds m-th nearest index

    // ---- certificate fallback: exact 32-round argmin over the stream ----
    if (ovf) {
        u64 minkeep = 0;
        for (int k = 0; k < KNH; ++k) {
            u64 best = ~0ull;
            for (int g = 0; g < L2; g += 64) {
                const int gp = g + lane;
                int lo = 0, hi = nsl - 1;
#pragma unroll
                for (int st = 0; st < 6; ++st) {
                    const int mid = (lo + hi + 1) >> 1;
                    const int v = __shfl(excl, mid);
                    const bool go = (v <= gp);
                    lo = go ? mid : lo;
                    hi = go ? hi : mid - 1;
                }
                const int cnd = __shfl(myc0, lo) + gp - __shfl(excl, lo);
                const int cc  = min(max(cnd, 0), NN - 1);
                const float2 pt = scb[cc];
                const int    jj = sjb[cc];
                const float dx = ci0 - pt.x, dy = ci1 - pt.y;
                const float d  = fmaf(dx, dx, dy * dy);
                const u64 kk = ((u64)__float_as_uint(d) << 32) | (u32)jj;
                if (gp < L2 && kk >= minkeep && kk < best) best = kk;
            }
            const u64 h = wave_min_u64(best);
            if (lane == k) jkeep = (int)(u32)h;
            minkeep = h + 1;
        }
    }

    // ---- gather 32 rows, f32 sum/sumsq (4 channels per lane) ----
    float s1[4] = {0.f, 0.f, 0.f, 0.f};
    float s2[4] = {0.f, 0.f, 0.f, 0.f};
    const float* xb = x + (size_t)b * NN * EE;
#pragma unroll 8
    for (int k = 0; k < KNH; ++k) {
        const int j = __builtin_amdgcn_readlane(jkeep, k);
        const float4 v = *reinterpret_cast<const float4*>(xb + (size_t)j * EE + (lane << 2));
        s1[0] += v.x; s2[0] += v.x * v.x;
        s1[1] += v.y; s2[1] += v.y * v.y;
        s1[2] += v.z; s2[2] += v.z * v.z;
        s1[3] += v.w; s2[3] += v.w * v.w;
    }

    const float* gmb = gm + b * EE;
    float tt = 0.f;
#pragma unroll
    for (int q = 0; q < 4; ++q) {
        const float sum = s1[q];
        float ssd = s2[q] - sum * sum * (1.0f / 32.0f);
        ssd = ssd > 0.f ? ssd : 0.f;
        const float ls = sqrtf(ssd * (1.0f / 31.0f));
        tt += ls / gmb[(lane << 2) + q];
    }
#pragma unroll
    for (int s2r = 1; s2r < 64; s2r <<= 1) tt += __shfl_xor(tt, s2r);

    if (lane == 0) ld_out[(size_t)b * NN + i] = tt;
}

// one wave per point: exact rank (desc, index tie-break) + direct row gather
__global__ void k_rank_gather(const float* __restrict__ x, const float* __restrict__ coords,
                              const float* __restrict__ ld,
                              float* __restrict__ x_out, float* __restrict__ c_out) {
    const int b    = blockIdx.y;
    const int wid  = threadIdx.x >> 6;
    const int lane = threadIdx.x & 63;
    const int i    = blockIdx.x * 4 + wid;
    const float* lb = ld + (size_t)b * NN;
    const float di = lb[i];
    int cnt = 0;
    for (int t = 0; t < NN / 256; ++t) {
        const int j0 = t * 256 + (lane << 2);
        const float4 dv = *reinterpret_cast<const float4*>(lb + j0);
        cnt += (dv.x > di || (dv.x == di && (j0 + 0) < i)) ? 1 : 0;
        cnt += (dv.y > di || (dv.y == di && (j0 + 1) < i)) ? 1 : 0;
        cnt += (dv.z > di || (dv.z == di && (j0 + 2) < i)) ? 1 : 0;
        cnt += (dv.w > di || (dv.w == di && (j0 + 3) < i)) ? 1 : 0;
    }
#pragma unroll
    for (int s = 1; s < 64; s <<= 1) cnt += __shfl_xor(cnt, s);

    if (cnt < NKEEP) {
        const float4 v = *reinterpret_cast<const float4*>(x + ((size_t)b * NN + i) * EE + (lane << 2));
        *reinterpret_cast<float4*>(x_out + ((size_t)b * NKEEP + cnt) * EE + (lane << 2)) = v;
        if (lane < 2) {
            c_out[((size_t)b * 2 + lane) * NKEEP + cnt] = coords[((size_t)b * 2 + lane) * NN + i];
        }
    }
}

extern "C" void kernel_launch(void* const* d_in, const int* in_sizes, int n_in,
                              void* d_out, int out_size, void* d_ws, size_t ws_size,
                              hipStream_t stream) {
    const float* x      = (const float*)d_in[0];
    const float* coords = (const float*)d_in[1];

    float* out    = (float*)d_out;
    float* x_out  = out;                 // [2][4096][256]
    float* c_out  = out + 2097152;       // [2][2][4096][1]
    float* ld_out = out + 2113536;       // [2][8192]

    char*   ws    = (char*)d_ws;
    float*  part  = (float*)(ws);
    float*  gm    = (float*)(ws + 65536);
    int*    start = (int*)  (ws + 67584);
    float2* sc    = (float2*)(ws + 100384);
    int*    sj    = (int*)  (ws + 231456);

    k_pre        <<<18,            1024, 0, stream>>>(coords, x, start, sc, sj, part);
    k_gm_final   <<<dim3(1, 2),    256,  0, stream>>>(part, gm);
    k_knn_dist   <<<4096,          256,  0, stream>>>(x, gm, sc, sj, start, ld_out);
    k_rank_gather<<<dim3(2048, 2), 256,  0, stream>>>(x, coords, ld_out, x_out, c_out);
}